// Round 5
// baseline (303.448 us; speedup 1.0000x reference)
//
#include <hip/hip_runtime.h>
#include <math.h>

typedef __attribute__((ext_vector_type(8))) short short8;
typedef __attribute__((ext_vector_type(4))) short short4v;
typedef __attribute__((ext_vector_type(4))) float floatx4;

#define AS1 __attribute__((address_space(1)))
#define AS3 __attribute__((address_space(3)))

__device__ inline void gload_lds16(const short* g, short* l) {
    __builtin_amdgcn_global_load_lds((const AS1 unsigned int*)g,
                                     (AS3 unsigned int*)l, 16, 0, 0);
}

__device__ inline short f2bf(float f) {
    unsigned u = __builtin_bit_cast(unsigned, f);
    u += 0x7fffu + ((u >> 16) & 1u);
    return (short)(u >> 16);
}

// ---------------------------------------------------------------------------
// x [8M] fp32 -> bf16
// ---------------------------------------------------------------------------
__global__ __launch_bounds__(256) void conv_x(
    const float* __restrict__ x, short* __restrict__ xb)
{
    int i = (blockIdx.x * 256 + threadIdx.x) * 4;
    float4 v = *(const float4*)&x[i];
    short4v o = { f2bf(v.x), f2bf(v.y), f2bf(v.z), f2bf(v.w) };
    *(short4v*)&xb[i] = o;
}

// ---------------------------------------------------------------------------
// Coalesced weight transpose + fp32->bf16 via 64x64 LDS tiles.
// Wall [3072,1024]: rows 0-1023 = Wq^T * (0.125*log2e), 1024-2047 = Wk^T,
// 2048-3071 = Wv^T.  WoT [1024,1024] = Wo^T.
// ---------------------------------------------------------------------------
__global__ __launch_bounds__(256) void transpose_w(
    const float* __restrict__ Wq, const float* __restrict__ Wk,
    const float* __restrict__ Wv, const float* __restrict__ Wo,
    short* __restrict__ Wall, short* __restrict__ WoT)
{
    __shared__ short T[64 * 72];
    const int kt = blockIdx.x, y = blockIdx.y;
    const int tid = threadIdx.x;
    const int lr = tid >> 2, lc = (tid & 3) * 16;
    #pragma unroll 1
    for (int m = 0; m < 4; ++m) {
        const float* src;
        float s = 1.f;
        if (m < 3) {
            const float* W = (m == 0) ? Wq : (m == 1) ? Wk : Wv;
            src = W + ((size_t)y << 16) + (size_t)(kt * 64 + lr) * 64 + lc;
            if (m == 0) s = 0.125f * 1.44269504088896f;   // 1/sqrt(D) * log2(e)
        } else {
            src = Wo + (size_t)(kt * 64 + lr) * 1024 + y * 64 + lc;
        }
        short8 t0, t1;
        {
            float4 v0 = *(const float4*)(src + 0);
            float4 v1 = *(const float4*)(src + 4);
            float4 v2 = *(const float4*)(src + 8);
            float4 v3 = *(const float4*)(src + 12);
            t0[0]=f2bf(v0.x*s); t0[1]=f2bf(v0.y*s); t0[2]=f2bf(v0.z*s); t0[3]=f2bf(v0.w*s);
            t0[4]=f2bf(v1.x*s); t0[5]=f2bf(v1.y*s); t0[6]=f2bf(v1.z*s); t0[7]=f2bf(v1.w*s);
            t1[0]=f2bf(v2.x*s); t1[1]=f2bf(v2.y*s); t1[2]=f2bf(v2.z*s); t1[3]=f2bf(v2.w*s);
            t1[4]=f2bf(v3.x*s); t1[5]=f2bf(v3.y*s); t1[6]=f2bf(v3.z*s); t1[7]=f2bf(v3.w*s);
        }
        *(short8*)&T[lr * 72 + lc]     = t0;
        *(short8*)&T[lr * 72 + lc + 8] = t1;
        __syncthreads();
        short8 o0, o1;
        #pragma unroll
        for (int j = 0; j < 8; ++j) o0[j] = T[(lc + j) * 72 + lr];
        #pragma unroll
        for (int j = 0; j < 8; ++j) o1[j] = T[(lc + 8 + j) * 72 + lr];
        short* dst = (m < 3)
            ? Wall + (size_t)(m * 1024 + y * 64 + lr) * 1024 + kt * 64
            : WoT  + (size_t)(y * 64 + lr) * 1024 + kt * 64;
        *(short8*)&dst[lc]     = o0;
        *(short8*)&dst[lc + 8] = o1;
        __syncthreads();
    }
}

// ---------------------------------------------------------------------------
// QKV: C = A[M,K] @ BT[N,K]^T, bf16 out.  Q -> C, K -> C+8M.
// V (plane 2) written directly transposed to Vt[b*16+h][d=64][t=2048].
//
// 128x128 tile, BK=64, 3-stage counted-vmcnt pipeline (T3+T4):
// three LDS K-tile buffers (96 KB), tiles t+1 and t+2 stay in flight while
// tile t computes -> ~1240 cyc prefetch lead per SIMD covers HBM latency.
// Raw s_barrier + inline vmcnt(8) (never 0 in steady state).
// Correctness: ds_reads of buf c feed MFMAs by data dependence (no hoist
// hazard); barrier-1 = all waves done reading buf c; vmcnt(8) retires tile
// t+1's 8 loads; barrier-2 = tile t+1 globally landed; G_ISSUE refills the
// freed buf c with tile t+3. Compute core, XOR swizzle and epilogue are
// verbatim the R2-proven kernel (0 bank conflicts).
// Grid 1536 @ 1 block/CU: XCD-chunked decode gives each XCD 3 B-panels
// (768 KB, L2-resident) and 3x in-L2 A-panel reuse.
// ---------------------------------------------------------------------------
__global__ __launch_bounds__(256, 1) void gemm_bt(
    const short* __restrict__ A, const short* __restrict__ BT,
    short* __restrict__ C, short* __restrict__ Vt, int M, int N, int K)
{
    __shared__ short As[3][128 * 64];
    __shared__ short Bs[3][128 * 64];
    const int tid  = threadIdx.x;
    const int wid  = tid >> 6, lane = tid & 63;
    const int quad = lane >> 4, l15 = lane & 15, l7 = l15 & 7;

    // decode: 8 XCDs x (64 m-panels x 3 n-panels); consecutive blocks share
    // an m-panel (A L2 reuse), each XCD owns n-panels [xcd*3, xcd*3+3)
    const int flat = blockIdx.x;
    const int xcd = flat & 7, local = flat >> 3;     // local 0..191
    const int n_panel = xcd * 3 + (local % 3);
    const int m_panel = local / 3;
    const int m0 = m_panel * 128, n0 = n_panel * 128;
    const int wr = (wid >> 1) * 64, wc = (wid & 1) * 64;

    floatx4 acc[4][4] = {};

    // staging: thread covers rows {srow + 32t}; chunk pre-swizzled by row&7
    const int srow = tid >> 3;                      // 0..31
    const int gcol = ((tid & 7) ^ (srow & 7)) * 8;  // (srow+32t)&7 == srow&7
    const int lrow = wid * 8;                       // wave-uniform LDS row base
    const int NT = K >> 6;                          // 16

    const short* aCur = A  + (size_t)(m0 + srow) * K + gcol;
    const short* bCur = BT + (size_t)(n0 + srow) * K + gcol;

#define G_ISSUE(c) do { \
    _Pragma("unroll") \
    for (int tt = 0; tt < 4; ++tt) { \
        gload_lds16(aCur + (size_t)(tt * 32) * K, &As[c][(tt * 32 + lrow) * 64]); \
        gload_lds16(bCur + (size_t)(tt * 32) * K, &Bs[c][(tt * 32 + lrow) * 64]); \
    } \
    aCur += 64; bCur += 64; } while (0)

    // prologue: tiles 0,1,2 in flight (24 loads); land tile 0 (oldest 8)
    G_ISSUE(0); G_ISSUE(1); G_ISSUE(2);
    asm volatile("s_waitcnt vmcnt(16)" ::: "memory");
    __builtin_amdgcn_s_barrier();
    asm volatile("" ::: "memory");

    int c = 0;
    for (int t = 0; t < NT; ++t) {
        const short* Ab = As[c];
        const short* Bb = Bs[c];
        #pragma unroll
        for (int ks = 0; ks < 2; ++ks) {
            short8 bfr[4], afr[4];
            #pragma unroll
            for (int j = 0; j < 4; ++j)
                bfr[j] = *(const short8*)&Bb[(wc + j * 16 + l15) * 64 +
                                             (((ks * 4 + quad) ^ l7) * 8)];
            #pragma unroll
            for (int i = 0; i < 4; ++i)
                afr[i] = *(const short8*)&Ab[(wr + i * 16 + l15) * 64 +
                                             (((ks * 4 + quad) ^ l7) * 8)];
            __builtin_amdgcn_s_setprio(1);
            #pragma unroll
            for (int i = 0; i < 4; ++i)
                #pragma unroll
                for (int j = 0; j < 4; ++j)
                    acc[i][j] = __builtin_amdgcn_mfma_f32_16x16x32_bf16(
                        afr[i], bfr[j], acc[i][j], 0, 0, 0);
            __builtin_amdgcn_s_setprio(0);
        }
        asm volatile("" ::: "memory");
        __builtin_amdgcn_s_barrier();               // all waves done reading buf c
        asm volatile("" ::: "memory");
        if (t + 3 <= NT) { asm volatile("s_waitcnt vmcnt(8)" ::: "memory"); }
        else             { asm volatile("s_waitcnt vmcnt(0)" ::: "memory"); }
        if (t + 3 < NT) G_ISSUE(c);                 // tile t+3 into freed buf c
        asm volatile("" ::: "memory");
        __builtin_amdgcn_s_barrier();               // tile t+1 globally landed
        asm volatile("" ::: "memory");
        c = (c == 2) ? 0 : c + 1;
    }
#undef G_ISSUE

    const int plane = n0 >> 10;                     // uniform per block
    #pragma unroll
    for (int i = 0; i < 4; ++i) {
        int row = m0 + wr + i * 16 + quad * 4;
        #pragma unroll
        for (int j = 0; j < 4; ++j) {
            int col = n0 + wc + j * 16 + l15;
            int c1 = col & 1023;
            if (plane < 2) {
                short* dst = C + (size_t)plane * 8192 * 1024;
                #pragma unroll
                for (int r = 0; r < 4; ++r)
                    dst[(size_t)(row + r) * 1024 + c1] = f2bf(acc[i][j][r]);
            } else {
                int b = row >> 11, t = row & 2047;
                int hb = b * 16 + (c1 >> 6), d = c1 & 63;
                short4v o = { f2bf(acc[i][j][0]), f2bf(acc[i][j][1]),
                              f2bf(acc[i][j][2]), f2bf(acc[i][j][3]) };
                *(short4v*)&Vt[((size_t)hb * 64 + d) * 2048 + t] = o;
            }
        }
    }
}

// ---------------------------------------------------------------------------
// O-projection GEMM: 64x128 tile (grid 128x8 = 1024 blocks -> 4 blocks/CU),
// BK=64 swizzled LDS (same scheme as gemm_bt). fp32 output + bias.
// ---------------------------------------------------------------------------
__global__ __launch_bounds__(256) void gemm_o(
    const short* __restrict__ A, const short* __restrict__ BT,
    float* __restrict__ Cf, const float* __restrict__ bias, int N, int K)
{
    __shared__ short As[64 * 64];
    __shared__ short Bs[128 * 64];
    const int tid  = threadIdx.x;
    const int wid  = tid >> 6, lane = tid & 63;
    const int quad = lane >> 4, l15 = lane & 15;
    const int l7 = l15 & 7;
    const int m0 = blockIdx.x * 64, n0 = blockIdx.y * 128;
    const int wr = (wid >> 1) * 32, wc = (wid & 1) * 64;

    floatx4 acc[2][4] = {};

    const int srow = tid >> 3;                         // 0..31
    const int gcol = ((tid & 7) ^ (srow & 7)) * 8;

    for (int k0 = 0; k0 < K; k0 += 64) {
        #pragma unroll
        for (int t = 0; t < 2; ++t)
            gload_lds16(A + (size_t)(m0 + srow + t * 32) * K + k0 + gcol,
                        &As[(t * 32 + wid * 8) * 64]);
        #pragma unroll
        for (int t = 0; t < 4; ++t)
            gload_lds16(BT + (size_t)(n0 + srow + t * 32) * K + k0 + gcol,
                        &Bs[(t * 32 + wid * 8) * 64]);
        __syncthreads();
        #pragma unroll
        for (int ks = 0; ks < 2; ++ks) {
            short8 bfr[4];
            #pragma unroll
            for (int j = 0; j < 4; ++j)
                bfr[j] = *(const short8*)&Bs[(wc + j * 16 + l15) * 64 +
                                             (((ks * 4 + quad) ^ l7) * 8)];
            #pragma unroll
            for (int i = 0; i < 2; ++i) {
                short8 afr = *(const short8*)&As[(wr + i * 16 + l15) * 64 +
                                                 (((ks * 4 + quad) ^ l7) * 8)];
                #pragma unroll
                for (int j = 0; j < 4; ++j)
                    acc[i][j] = __builtin_amdgcn_mfma_f32_16x16x32_bf16(
                        afr, bfr[j], acc[i][j], 0, 0, 0);
            }
        }
        __syncthreads();
    }

    #pragma unroll
    for (int i = 0; i < 2; ++i) {
        int row = m0 + wr + i * 16 + quad * 4;
        #pragma unroll
        for (int j = 0; j < 4; ++j) {
            int col = n0 + wc + j * 16 + l15;
            float bv = bias[col];
            #pragma unroll
            for (int r = 0; r < 4; ++r)
                Cf[(size_t)(row + r) * N + col] = acc[i][j][r] + bv;
        }
    }
}

// ---------------------------------------------------------------------------
// Flash attention, causal, non-online softmax. Q pre-scaled by log2e/sqrt(D);
// exp via raw v_exp_f32. Row-sums l via ones-MFMA. P quantize = truncation
// (consistent numerator/denominator).
// K/V staged by global_load_lds into XOR-swizzled unpadded tiles;
// double-buffered; single end-of-iter barrier drains next tile's loads.
// Grid = 1024 blocks; decode keeps all 16 q-tiles of one (b,h) on one XCD
// (L2-resident K/V) and launches long q-tiles first.
// ---------------------------------------------------------------------------
__global__ __launch_bounds__(256) void attn_fwd(
    const short* __restrict__ Q, const short* __restrict__ Kg,
    const short* __restrict__ Vt_g, short* __restrict__ O)
{
    __shared__ short Ks[2][64 * 64];
    __shared__ short Vs[2][64 * 64];
    __shared__ short Pb[4 * 32 * 72];
    const int tid  = threadIdx.x;
    const int wid  = tid >> 6, lane = tid & 63;
    const int quad = lane >> 4, l15 = lane & 15;

    // block decode: XCD = flat&7; 8 (b,h) pairs per XCD; long q-tiles first
    const int flat = blockIdx.x;
    const int xr = flat & 7;
    const int qq = flat >> 3;
    const int qt = 15 - (qq >> 3);
    const int hb = xr * 8 + (qq & 7);
    const int h = hb & 15, b = hb >> 4;

    const size_t base  = ((size_t)b * 2048) * 1024 + h * 64;
    const size_t vbase = ((size_t)(b * 16 + h)) * 64 * 2048;
    short* Pw = &Pb[wid * 32 * 72];

    const int srow = tid >> 3;                         // 0..31
    const int gcol = ((tid & 7) ^ (srow & 7)) * 8;     // (srow+32)&7 == srow&7
    const int lbase0 = (wid * 8) * 64;                 // wave-uniform LDS bases
    const int lbase1 = (wid * 8 + 32) * 64;
    const int l7 = l15 & 7;

    const short one_bf = (short)0x3F80;                // bf16 1.0
    const short8 bones = { one_bf, one_bf, one_bf, one_bf,
                           one_bf, one_bf, one_bf, one_bf };

    short8 qf[2][2];
    #pragma unroll
    for (int mt = 0; mt < 2; ++mt)
        #pragma unroll
        for (int ks = 0; ks < 2; ++ks)
            qf[mt][ks] = *(const short8*)&Q[base +
                (size_t)(qt * 128 + wid * 32 + mt * 16 + l15) * 1024 + ks * 32 + quad * 8];

    floatx4 oacc[2][4] = {};
    floatx4 lacc[2] = {};
    const int dst = 2 * qt + (wid >> 1);
    const int nst = 2 * qt + 2;

    const short* kptr = Kg + base + (size_t)srow * 1024 + gcol;
    const short* vptr = Vt_g + vbase + (size_t)srow * 2048 + gcol;

    // prologue: issue tile 0 into buf 0
    gload_lds16(kptr,               &Ks[0][lbase0]);
    gload_lds16(kptr + 32 * 1024,   &Ks[0][lbase1]);
    gload_lds16(vptr,               &Vs[0][lbase0]);
    gload_lds16(vptr + 32 * 2048,   &Vs[0][lbase1]);
    kptr += 64 * 1024; vptr += 64;
    __syncthreads();

    for (int st = 0; st < nst; ++st) {
        const short* K0 = Ks[st & 1];
        const short* V0 = Vs[st & 1];
        if (st + 1 < nst) {
            short* K1 = Ks[(st + 1) & 1];
            short* V1 = Vs[(st + 1) & 1];
            gload_lds16(kptr,             &K1[lbase0]);
            gload_lds16(kptr + 32 * 1024, &K1[lbase1]);
            gload_lds16(vptr,             &V1[lbase0]);
            gload_lds16(vptr + 32 * 2048, &V1[lbase1]);
            kptr += 64 * 1024; vptr += 64;
        }

        if (st <= dst) {
            floatx4 sf[2][4];
            #pragma unroll
            for (int nt = 0; nt < 4; ++nt) {
                floatx4 z0 = {}, z1 = {};
                #pragma unroll
                for (int ks = 0; ks < 2; ++ks) {
                    short8 bfr = *(const short8*)&K0[(nt * 16 + l15) * 64 +
                                                     (((ks * 4 + quad) ^ l7) * 8)];
                    z0 = __builtin_amdgcn_mfma_f32_16x16x32_bf16(qf[0][ks], bfr, z0, 0, 0, 0);
                    z1 = __builtin_amdgcn_mfma_f32_16x16x32_bf16(qf[1][ks], bfr, z1, 0, 0, 0);
                }
                sf[0][nt] = z0; sf[1][nt] = z1;
            }

            if (st == dst) {
                #pragma unroll
                for (int mt = 0; mt < 2; ++mt)
                    #pragma unroll
                    for (int nt = 0; nt < 4; ++nt)
                        #pragma unroll
                        for (int r = 0; r < 4; ++r) {
                            int qa = qt * 128 + wid * 32 + mt * 16 + quad * 4 + r;
                            int sa = st * 64 + nt * 16 + l15;
                            if (sa > qa) sf[mt][nt][r] = -INFINITY;
                        }
            }

            #pragma unroll
            for (int mt = 0; mt < 2; ++mt)
                #pragma unroll
                for (int nt = 0; nt < 4; ++nt)
                    #pragma unroll
                    for (int r = 0; r < 4; ++r) {
                        float p = __builtin_amdgcn_exp2f(sf[mt][nt][r]);
                        unsigned u = __builtin_bit_cast(unsigned, p);
                        Pw[(mt * 16 + quad * 4 + r) * 72 + ((nt ^ quad) * 16) + l15] =
                            (short)(u >> 16);
                    }
            // no barrier: P is wave-private

            #pragma unroll
            for (int ks = 0; ks < 2; ++ks) {
                int blk = (ks * 2 + (quad >> 1)) ^ (l15 >> 2);
                short8 af0 = *(const short8*)&Pw[(l15) * 72 + blk * 16 + (quad & 1) * 8];
                short8 af1 = *(const short8*)&Pw[(16 + l15) * 72 + blk * 16 + (quad & 1) * 8];
                lacc[0] = __builtin_amdgcn_mfma_f32_16x16x32_bf16(af0, bones, lacc[0], 0, 0, 0);
                lacc[1] = __builtin_amdgcn_mfma_f32_16x16x32_bf16(af1, bones, lacc[1], 0, 0, 0);
                #pragma unroll
                for (int nt = 0; nt < 4; ++nt) {
                    short8 bfr = *(const short8*)&V0[(nt * 16 + l15) * 64 +
                                                     (((ks * 4 + quad) ^ l7) * 8)];
                    oacc[0][nt] = __builtin_amdgcn_mfma_f32_16x16x32_bf16(af0, bfr, oacc[0][nt], 0, 0, 0);
                    oacc[1][nt] = __builtin_amdgcn_mfma_f32_16x16x32_bf16(af1, bfr, oacc[1][nt], 0, 0, 0);
                }
            }
        }
        __syncthreads();   // drains next tile's global_load_lds too
    }

    #pragma unroll
    for (int mt = 0; mt < 2; ++mt)
        #pragma unroll
        for (int nt = 0; nt < 4; ++nt)
            #pragma unroll
            for (int r = 0; r < 4; ++r) {
                float v = oacc[mt][nt][r] / lacc[mt][r];
                int qa = qt * 128 + wid * 32 + mt * 16 + quad * 4 + r;
                O[base + (size_t)qa * 1024 + nt * 16 + l15] = f2bf(v);
            }
}

// ---------------------------------------------------------------------------
// Workspace (40 MB):
//   ws[ 0..16): xb (QKV-gemm input) -> Ao (attn output; xb dead after gemm_bt)
//   ws[16..32): Vt (written transposed by gemm_bt, read by attn_fwd)
//   ws[32..38): Wall = [Wq^T*c | Wk^T | Wv^T]   ws[38..40): WoT
//   d_out: Qp (lo 16MB) + Kp (hi 16MB); overwritten by gemm_o's fp32 output
//   (gemm_o reads Ao from ws, so no read/write overlap).
// ---------------------------------------------------------------------------
extern "C" void kernel_launch(void* const* d_in, const int* in_sizes, int n_in,
                              void* d_out, int out_size, void* d_ws, size_t ws_size,
                              hipStream_t stream) {
    const float* x  = (const float*)d_in[0];
    const float* Wq = (const float*)d_in[1];
    const float* Wk = (const float*)d_in[2];
    const float* Wv = (const float*)d_in[3];
    const float* Wo = (const float*)d_in[4];
    const float* bo = (const float*)d_in[5];
    float* out = (float*)d_out;

    char* ws = (char*)d_ws;
    const size_t MB = 1024 * 1024;
    short* xb   = (short*)(ws + 0 * MB);
    short* Ao   = (short*)(ws + 0 * MB);    // overlays xb (dead after QKV gemm)
    short* Vt_g = (short*)(ws + 16 * MB);
    short* Wall = (short*)(ws + 32 * MB);
    short* WoT  = (short*)(ws + 38 * MB);
    short* Qp   = (short*)d_out;            // d_out lo
    short* Kp   = Qp + 8 * 1024 * 1024;     // d_out hi

    conv_x<<<8192, 256, 0, stream>>>(x, xb);
    transpose_w<<<dim3(16, 16), 256, 0, stream>>>(Wq, Wk, Wv, Wo, Wall, WoT);

    gemm_bt<<<1536, 256, 0, stream>>>(xb, Wall, Qp, Vt_g, 8192, 3072, 1024);

    attn_fwd<<<1024, 256, 0, stream>>>(Qp, Kp, Vt_g, Ao);

    gemm_o<<<dim3(128, 8), 256, 0, stream>>>(Ao, WoT, out, bo, 1024, 1024);
}

// Round 6
// 245.041 us; speedup vs baseline: 1.2384x; 1.2384x over previous
//
#include <hip/hip_runtime.h>
#include <math.h>

typedef __attribute__((ext_vector_type(8))) short short8;
typedef __attribute__((ext_vector_type(4))) short short4v;
typedef __attribute__((ext_vector_type(4))) float floatx4;

#define AS1 __attribute__((address_space(1)))
#define AS3 __attribute__((address_space(3)))

__device__ inline void gload_lds16(const short* g, short* l) {
    __builtin_amdgcn_global_load_lds((const AS1 unsigned int*)g,
                                     (AS3 unsigned int*)l, 16, 0, 0);
}

__device__ inline short f2bf(float f) {
    unsigned u = __builtin_bit_cast(unsigned, f);
    u += 0x7fffu + ((u >> 16) & 1u);
    return (short)(u >> 16);
}

// ---------------------------------------------------------------------------
// x [8M] fp32 -> bf16
// ---------------------------------------------------------------------------
__global__ __launch_bounds__(256) void conv_x(
    const float* __restrict__ x, short* __restrict__ xb)
{
    int i = (blockIdx.x * 256 + threadIdx.x) * 4;
    float4 v = *(const float4*)&x[i];
    short4v o = { f2bf(v.x), f2bf(v.y), f2bf(v.z), f2bf(v.w) };
    *(short4v*)&xb[i] = o;
}

// ---------------------------------------------------------------------------
// Coalesced weight transpose + fp32->bf16 via 64x64 LDS tiles.
// Wall [3072,1024]: rows 0-1023 = Wq^T * (0.125*log2e), 1024-2047 = Wk^T,
// 2048-3071 = Wv^T.  WoT [1024,1024] = Wo^T.
// ---------------------------------------------------------------------------
__global__ __launch_bounds__(256) void transpose_w(
    const float* __restrict__ Wq, const float* __restrict__ Wk,
    const float* __restrict__ Wv, const float* __restrict__ Wo,
    short* __restrict__ Wall, short* __restrict__ WoT)
{
    __shared__ short T[64 * 72];
    const int kt = blockIdx.x, y = blockIdx.y;
    const int tid = threadIdx.x;
    const int lr = tid >> 2, lc = (tid & 3) * 16;
    #pragma unroll 1
    for (int m = 0; m < 4; ++m) {
        const float* src;
        float s = 1.f;
        if (m < 3) {
            const float* W = (m == 0) ? Wq : (m == 1) ? Wk : Wv;
            src = W + ((size_t)y << 16) + (size_t)(kt * 64 + lr) * 64 + lc;
            if (m == 0) s = 0.125f * 1.44269504088896f;   // 1/sqrt(D) * log2(e)
        } else {
            src = Wo + (size_t)(kt * 64 + lr) * 1024 + y * 64 + lc;
        }
        short8 t0, t1;
        {
            float4 v0 = *(const float4*)(src + 0);
            float4 v1 = *(const float4*)(src + 4);
            float4 v2 = *(const float4*)(src + 8);
            float4 v3 = *(const float4*)(src + 12);
            t0[0]=f2bf(v0.x*s); t0[1]=f2bf(v0.y*s); t0[2]=f2bf(v0.z*s); t0[3]=f2bf(v0.w*s);
            t0[4]=f2bf(v1.x*s); t0[5]=f2bf(v1.y*s); t0[6]=f2bf(v1.z*s); t0[7]=f2bf(v1.w*s);
            t1[0]=f2bf(v2.x*s); t1[1]=f2bf(v2.y*s); t1[2]=f2bf(v2.z*s); t1[3]=f2bf(v2.w*s);
            t1[4]=f2bf(v3.x*s); t1[5]=f2bf(v3.y*s); t1[6]=f2bf(v3.z*s); t1[7]=f2bf(v3.w*s);
        }
        *(short8*)&T[lr * 72 + lc]     = t0;
        *(short8*)&T[lr * 72 + lc + 8] = t1;
        __syncthreads();
        short8 o0, o1;
        #pragma unroll
        for (int j = 0; j < 8; ++j) o0[j] = T[(lc + j) * 72 + lr];
        #pragma unroll
        for (int j = 0; j < 8; ++j) o1[j] = T[(lc + 8 + j) * 72 + lr];
        short* dst = (m < 3)
            ? Wall + (size_t)(m * 1024 + y * 64 + lr) * 1024 + kt * 64
            : WoT  + (size_t)(y * 64 + lr) * 1024 + kt * 64;
        *(short8*)&dst[lc]     = o0;
        *(short8*)&dst[lc + 8] = o1;
        __syncthreads();
    }
}

// ---------------------------------------------------------------------------
// QKV: C = A[M,K] @ BT[N,K]^T, bf16 out.  Q -> C, K -> C+8M.
// V (plane 2) written directly transposed to Vt[b*16+h][d=64][t=2048].
// 128x128 tile, BK=64, single-buffered 2-barrier loop at 5 blocks/CU
// (R2-proven: 67.7 us, 0 bank conflicts; TLP hides staging latency --
// R4/R5 showed explicit pipelining at lower occupancy only regresses).
// XOR swizzle chunk' = chunk ^ (row&7): global source pre-swizzled for
// global_load_lds (linear dest), fragment reads undo it.
// ---------------------------------------------------------------------------
__global__ __launch_bounds__(256) void gemm_bt(
    const short* __restrict__ A, const short* __restrict__ BT,
    short* __restrict__ C, short* __restrict__ Vt, int M, int N, int K)
{
    __shared__ short As[128 * 64];
    __shared__ short Bs[128 * 64];
    const int tid  = threadIdx.x;
    const int wid  = tid >> 6, lane = tid & 63;
    const int quad = lane >> 4, l15 = lane & 15;
    const int l7 = l15 & 7;
    const int m0 = blockIdx.x * 128, n0 = blockIdx.y * 128;
    const int wr = (wid >> 1) * 64, wc = (wid & 1) * 64;

    floatx4 acc[4][4] = {};

    // staging: row = srow + t*32 (t=0..3), chunk pre-swizzled by row&7
    const int srow = tid >> 3;                         // 0..31
    const int gcol = ((tid & 7) ^ (srow & 7)) * 8;     // (row&7) == srow&7 for all t

    for (int k0 = 0; k0 < K; k0 += 64) {
        #pragma unroll
        for (int t = 0; t < 4; ++t) {
            gload_lds16(A  + (size_t)(m0 + srow + t * 32) * K + k0 + gcol,
                        &As[(t * 32 + wid * 8) * 64]);
            gload_lds16(BT + (size_t)(n0 + srow + t * 32) * K + k0 + gcol,
                        &Bs[(t * 32 + wid * 8) * 64]);
        }
        __syncthreads();
        #pragma unroll
        for (int ks = 0; ks < 2; ++ks) {
            short8 bfr[4];
            #pragma unroll
            for (int j = 0; j < 4; ++j)
                bfr[j] = *(const short8*)&Bs[(wc + j * 16 + l15) * 64 +
                                             (((ks * 4 + quad) ^ l7) * 8)];
            #pragma unroll
            for (int i = 0; i < 4; ++i) {
                short8 afr = *(const short8*)&As[(wr + i * 16 + l15) * 64 +
                                                 (((ks * 4 + quad) ^ l7) * 8)];
                #pragma unroll
                for (int j = 0; j < 4; ++j)
                    acc[i][j] = __builtin_amdgcn_mfma_f32_16x16x32_bf16(
                        afr, bfr[j], acc[i][j], 0, 0, 0);
            }
        }
        __syncthreads();
    }

    const int plane = n0 >> 10;                        // uniform per block
    #pragma unroll
    for (int i = 0; i < 4; ++i) {
        int row = m0 + wr + i * 16 + quad * 4;
        #pragma unroll
        for (int j = 0; j < 4; ++j) {
            int col = n0 + wc + j * 16 + l15;
            int c1 = col & 1023;
            if (plane < 2) {
                short* dst = C + (size_t)plane * 8192 * 1024;
                #pragma unroll
                for (int r = 0; r < 4; ++r)
                    dst[(size_t)(row + r) * 1024 + c1] = f2bf(acc[i][j][r]);
            } else {
                int b = row >> 11, t = row & 2047;
                int hb = b * 16 + (c1 >> 6), d = c1 & 63;
                short4v o = { f2bf(acc[i][j][0]), f2bf(acc[i][j][1]),
                              f2bf(acc[i][j][2]), f2bf(acc[i][j][3]) };
                *(short4v*)&Vt[((size_t)hb * 64 + d) * 2048 + t] = o;
            }
        }
    }
}

// ---------------------------------------------------------------------------
// O-projection GEMM: 64x128 tile, 1024 blocks -> 4 blocks/CU, BK=64 swizzled
// LDS (gemm_bt scheme). Flat grid with bijective XCD decode: each XCD owns
// exactly one 128-col B-panel (256 KB, L2-resident). fp32 output + bias.
// ---------------------------------------------------------------------------
__global__ __launch_bounds__(256) void gemm_o(
    const short* __restrict__ A, const short* __restrict__ BT,
    float* __restrict__ Cf, const float* __restrict__ bias, int N, int K)
{
    __shared__ short As[64 * 64];
    __shared__ short Bs[128 * 64];
    const int tid  = threadIdx.x;
    const int wid  = tid >> 6, lane = tid & 63;
    const int quad = lane >> 4, l15 = lane & 15;
    const int l7 = l15 & 7;
    const int flat = blockIdx.x;                       // 1024 = 8 XCD x 128
    const int xcd = flat & 7, local = flat >> 3;       // local 0..127
    const int m0 = local * 64, n0 = xcd * 128;
    const int wr = (wid >> 1) * 32, wc = (wid & 1) * 64;

    floatx4 acc[2][4] = {};

    const int srow = tid >> 3;                         // 0..31
    const int gcol = ((tid & 7) ^ (srow & 7)) * 8;

    for (int k0 = 0; k0 < K; k0 += 64) {
        #pragma unroll
        for (int t = 0; t < 2; ++t)
            gload_lds16(A + (size_t)(m0 + srow + t * 32) * K + k0 + gcol,
                        &As[(t * 32 + wid * 8) * 64]);
        #pragma unroll
        for (int t = 0; t < 4; ++t)
            gload_lds16(BT + (size_t)(n0 + srow + t * 32) * K + k0 + gcol,
                        &Bs[(t * 32 + wid * 8) * 64]);
        __syncthreads();
        #pragma unroll
        for (int ks = 0; ks < 2; ++ks) {
            short8 bfr[4];
            #pragma unroll
            for (int j = 0; j < 4; ++j)
                bfr[j] = *(const short8*)&Bs[(wc + j * 16 + l15) * 64 +
                                             (((ks * 4 + quad) ^ l7) * 8)];
            #pragma unroll
            for (int i = 0; i < 2; ++i) {
                short8 afr = *(const short8*)&As[(wr + i * 16 + l15) * 64 +
                                                 (((ks * 4 + quad) ^ l7) * 8)];
                #pragma unroll
                for (int j = 0; j < 4; ++j)
                    acc[i][j] = __builtin_amdgcn_mfma_f32_16x16x32_bf16(
                        afr, bfr[j], acc[i][j], 0, 0, 0);
            }
        }
        __syncthreads();
    }

    #pragma unroll
    for (int i = 0; i < 2; ++i) {
        int row = m0 + wr + i * 16 + quad * 4;
        #pragma unroll
        for (int j = 0; j < 4; ++j) {
            int col = n0 + wc + j * 16 + l15;
            float bv = bias[col];
            #pragma unroll
            for (int r = 0; r < 4; ++r)
                Cf[(size_t)(row + r) * N + col] = acc[i][j][r] + bv;
        }
    }
}

// ---------------------------------------------------------------------------
// Flash attention, causal, non-online softmax. Q pre-scaled by log2e/sqrt(D);
// exp via raw v_exp_f32. Row-sums l via ones-MFMA. P quantize = truncation
// (consistent numerator/denominator).
// K/V staged by global_load_lds into XOR-swizzled unpadded tiles;
// double-buffered; single end-of-iter barrier drains next tile's loads.
// Grid = 1024 blocks; decode keeps all 16 q-tiles of one (b,h) on one XCD
// (L2-resident K/V) and launches long q-tiles first.
// T5: s_setprio(1) around the QK and PV MFMA clusters (attn blocks run at
// independent phases -> scheduler has roles to arbitrate; proven +4-7%).
// ---------------------------------------------------------------------------
__global__ __launch_bounds__(256) void attn_fwd(
    const short* __restrict__ Q, const short* __restrict__ Kg,
    const short* __restrict__ Vt_g, short* __restrict__ O)
{
    __shared__ short Ks[2][64 * 64];
    __shared__ short Vs[2][64 * 64];
    __shared__ short Pb[4 * 32 * 72];
    const int tid  = threadIdx.x;
    const int wid  = tid >> 6, lane = tid & 63;
    const int quad = lane >> 4, l15 = lane & 15;

    // block decode: XCD = flat&7; 8 (b,h) pairs per XCD; long q-tiles first
    const int flat = blockIdx.x;
    const int xr = flat & 7;
    const int qq = flat >> 3;
    const int qt = 15 - (qq >> 3);
    const int hb = xr * 8 + (qq & 7);
    const int h = hb & 15, b = hb >> 4;

    const size_t base  = ((size_t)b * 2048) * 1024 + h * 64;
    const size_t vbase = ((size_t)(b * 16 + h)) * 64 * 2048;
    short* Pw = &Pb[wid * 32 * 72];

    const int srow = tid >> 3;                         // 0..31
    const int gcol = ((tid & 7) ^ (srow & 7)) * 8;     // (srow+32)&7 == srow&7
    const int lbase0 = (wid * 8) * 64;                 // wave-uniform LDS bases
    const int lbase1 = (wid * 8 + 32) * 64;
    const int l7 = l15 & 7;

    const short one_bf = (short)0x3F80;                // bf16 1.0
    const short8 bones = { one_bf, one_bf, one_bf, one_bf,
                           one_bf, one_bf, one_bf, one_bf };

    short8 qf[2][2];
    #pragma unroll
    for (int mt = 0; mt < 2; ++mt)
        #pragma unroll
        for (int ks = 0; ks < 2; ++ks)
            qf[mt][ks] = *(const short8*)&Q[base +
                (size_t)(qt * 128 + wid * 32 + mt * 16 + l15) * 1024 + ks * 32 + quad * 8];

    floatx4 oacc[2][4] = {};
    floatx4 lacc[2] = {};
    const int dst = 2 * qt + (wid >> 1);
    const int nst = 2 * qt + 2;

    const short* kptr = Kg + base + (size_t)srow * 1024 + gcol;
    const short* vptr = Vt_g + vbase + (size_t)srow * 2048 + gcol;

    // prologue: issue tile 0 into buf 0
    gload_lds16(kptr,               &Ks[0][lbase0]);
    gload_lds16(kptr + 32 * 1024,   &Ks[0][lbase1]);
    gload_lds16(vptr,               &Vs[0][lbase0]);
    gload_lds16(vptr + 32 * 2048,   &Vs[0][lbase1]);
    kptr += 64 * 1024; vptr += 64;
    __syncthreads();

    for (int st = 0; st < nst; ++st) {
        const short* K0 = Ks[st & 1];
        const short* V0 = Vs[st & 1];
        if (st + 1 < nst) {
            short* K1 = Ks[(st + 1) & 1];
            short* V1 = Vs[(st + 1) & 1];
            gload_lds16(kptr,             &K1[lbase0]);
            gload_lds16(kptr + 32 * 1024, &K1[lbase1]);
            gload_lds16(vptr,             &V1[lbase0]);
            gload_lds16(vptr + 32 * 2048, &V1[lbase1]);
            kptr += 64 * 1024; vptr += 64;
        }

        if (st <= dst) {
            floatx4 sf[2][4];
            __builtin_amdgcn_s_setprio(1);
            #pragma unroll
            for (int nt = 0; nt < 4; ++nt) {
                floatx4 z0 = {}, z1 = {};
                #pragma unroll
                for (int ks = 0; ks < 2; ++ks) {
                    short8 bfr = *(const short8*)&K0[(nt * 16 + l15) * 64 +
                                                     (((ks * 4 + quad) ^ l7) * 8)];
                    z0 = __builtin_amdgcn_mfma_f32_16x16x32_bf16(qf[0][ks], bfr, z0, 0, 0, 0);
                    z1 = __builtin_amdgcn_mfma_f32_16x16x32_bf16(qf[1][ks], bfr, z1, 0, 0, 0);
                }
                sf[0][nt] = z0; sf[1][nt] = z1;
            }
            __builtin_amdgcn_s_setprio(0);

            if (st == dst) {
                #pragma unroll
                for (int mt = 0; mt < 2; ++mt)
                    #pragma unroll
                    for (int nt = 0; nt < 4; ++nt)
                        #pragma unroll
                        for (int r = 0; r < 4; ++r) {
                            int qa = qt * 128 + wid * 32 + mt * 16 + quad * 4 + r;
                            int sa = st * 64 + nt * 16 + l15;
                            if (sa > qa) sf[mt][nt][r] = -INFINITY;
                        }
            }

            #pragma unroll
            for (int mt = 0; mt < 2; ++mt)
                #pragma unroll
                for (int nt = 0; nt < 4; ++nt)
                    #pragma unroll
                    for (int r = 0; r < 4; ++r) {
                        float p = __builtin_amdgcn_exp2f(sf[mt][nt][r]);
                        unsigned u = __builtin_bit_cast(unsigned, p);
                        Pw[(mt * 16 + quad * 4 + r) * 72 + ((nt ^ quad) * 16) + l15] =
                            (short)(u >> 16);
                    }
            // no barrier: P is wave-private

            __builtin_amdgcn_s_setprio(1);
            #pragma unroll
            for (int ks = 0; ks < 2; ++ks) {
                int blk = (ks * 2 + (quad >> 1)) ^ (l15 >> 2);
                short8 af0 = *(const short8*)&Pw[(l15) * 72 + blk * 16 + (quad & 1) * 8];
                short8 af1 = *(const short8*)&Pw[(16 + l15) * 72 + blk * 16 + (quad & 1) * 8];
                lacc[0] = __builtin_amdgcn_mfma_f32_16x16x32_bf16(af0, bones, lacc[0], 0, 0, 0);
                lacc[1] = __builtin_amdgcn_mfma_f32_16x16x32_bf16(af1, bones, lacc[1], 0, 0, 0);
                #pragma unroll
                for (int nt = 0; nt < 4; ++nt) {
                    short8 bfr = *(const short8*)&V0[(nt * 16 + l15) * 64 +
                                                     (((ks * 4 + quad) ^ l7) * 8)];
                    oacc[0][nt] = __builtin_amdgcn_mfma_f32_16x16x32_bf16(af0, bfr, oacc[0][nt], 0, 0, 0);
                    oacc[1][nt] = __builtin_amdgcn_mfma_f32_16x16x32_bf16(af1, bfr, oacc[1][nt], 0, 0, 0);
                }
            }
            __builtin_amdgcn_s_setprio(0);
        }
        __syncthreads();   // drains next tile's global_load_lds too
    }

    #pragma unroll
    for (int mt = 0; mt < 2; ++mt)
        #pragma unroll
        for (int nt = 0; nt < 4; ++nt)
            #pragma unroll
            for (int r = 0; r < 4; ++r) {
                float v = oacc[mt][nt][r] / lacc[mt][r];
                int qa = qt * 128 + wid * 32 + mt * 16 + quad * 4 + r;
                O[base + (size_t)qa * 1024 + nt * 16 + l15] = f2bf(v);
            }
}

// ---------------------------------------------------------------------------
// Workspace (40 MB):
//   ws[ 0..16): xb (QKV-gemm input) -> Ao (attn output; xb dead after gemm_bt)
//   ws[16..32): Vt (written transposed by gemm_bt, read by attn_fwd)
//   ws[32..38): Wall = [Wq^T*c | Wk^T | Wv^T]   ws[38..40): WoT
//   d_out: Qp (lo 16MB) + Kp (hi 16MB); overwritten by gemm_o's fp32 output
//   (gemm_o reads Ao from ws, so no read/write overlap).
// ---------------------------------------------------------------------------
extern "C" void kernel_launch(void* const* d_in, const int* in_sizes, int n_in,
                              void* d_out, int out_size, void* d_ws, size_t ws_size,
                              hipStream_t stream) {
    const float* x  = (const float*)d_in[0];
    const float* Wq = (const float*)d_in[1];
    const float* Wk = (const float*)d_in[2];
    const float* Wv = (const float*)d_in[3];
    const float* Wo = (const float*)d_in[4];
    const float* bo = (const float*)d_in[5];
    float* out = (float*)d_out;

    char* ws = (char*)d_ws;
    const size_t MB = 1024 * 1024;
    short* xb   = (short*)(ws + 0 * MB);
    short* Ao   = (short*)(ws + 0 * MB);    // overlays xb (dead after QKV gemm)
    short* Vt_g = (short*)(ws + 16 * MB);
    short* Wall = (short*)(ws + 32 * MB);
    short* WoT  = (short*)(ws + 38 * MB);
    short* Qp   = (short*)d_out;            // d_out lo
    short* Kp   = Qp + 8 * 1024 * 1024;     // d_out hi

    conv_x<<<8192, 256, 0, stream>>>(x, xb);
    transpose_w<<<dim3(16, 16), 256, 0, stream>>>(Wq, Wk, Wv, Wo, Wall, WoT);

    gemm_bt<<<dim3(64, 24), 256, 0, stream>>>(xb, Wall, Qp, Vt_g, 8192, 3072, 1024);

    attn_fwd<<<1024, 256, 0, stream>>>(Qp, Kp, Vt_g, Ao);

    gemm_o<<<1024, 256, 0, stream>>>(Ao, WoT, out, bo, 1024, 1024);
}